// Round 5
// baseline (422.654 us; speedup 1.0000x reference)
//
#include <hip/hip_runtime.h>
#include <hip/hip_bf16.h>

#define B_ 4
#define S_ 2048
#define D_ 1024
#define H_ 16
#define HD_ 64

typedef __attribute__((ext_vector_type(8))) short bf16x8;
typedef __attribute__((ext_vector_type(4))) float f32x4;

#define MFMA32(a, b, c) __builtin_amdgcn_mfma_f32_16x16x32_bf16(a, b, c, 0, 0, 0)

__device__ __forceinline__ float fast_exp2(float x) {
#if __has_builtin(__builtin_amdgcn_exp2f)
  return __builtin_amdgcn_exp2f(x);
#else
  return exp2f(x);
#endif
}

__device__ __forceinline__ float fast_rcp(float x) {
#if __has_builtin(__builtin_amdgcn_rcpf)
  return __builtin_amdgcn_rcpf(x);
#else
  return 1.0f / x;
#endif
}

__device__ __forceinline__ short f2bf(float x) {
  union { float f; unsigned u; } v; v.f = x;
  unsigned r = (v.u + 0x7fffu + ((v.u >> 16) & 1u)) >> 16;
  return (short)(r & 0xffffu);
}

// single v_perm_b32 truncation pack: dst = (hi16(b)<<16)|hi16(a).
// Truncation bias cancels in softmax ratio (lsum sums the SAME truncated P).
__device__ __forceinline__ unsigned pack_hi16(float a, float b) {
  union { float f; unsigned u; } ua, ub; ua.f = a; ub.f = b;
  return __builtin_amdgcn_perm(ub.u, ua.u, 0x07060302u);
}

// async global->LDS DMA, 16 B per lane; LDS dest = wave-uniform base + lane*16.
__device__ __forceinline__ void gl_lds16(const short* g, void* l) {
  __builtin_amdgcn_global_load_lds(
      (const __attribute__((address_space(1))) unsigned*)(const void*)g,
      (__attribute__((address_space(3))) unsigned*)l, 16, 0, 0);
}

// ---------------- Kernel 1: QKV projections via MFMA (+ fused Wo convert) ---
// t = bid>>10: 0=V, 1=K, 2=Q, 3=Wo-convert (512 blocks appended to the grid
// to kill the separate wo_convert launch boundary).
__global__ __launch_bounds__(256) void qkv_proj2(
    const float* __restrict__ inpV, const float* __restrict__ inpK,
    const float* __restrict__ inpQ, const float* __restrict__ Wv,
    const float* __restrict__ Wk, const float* __restrict__ Wq,
    const float* __restrict__ Wo, short* __restrict__ wob,
    short* __restrict__ vt, short* __restrict__ kp, short* __restrict__ qp) {
  __shared__ bf16x8 xbuf[1024];  // 128 rows x 8 groups (16KB), g^=row&7
  __shared__ bf16x8 wbuf[512];   // 64 rows x 8 groups (8KB), g^=row&7
  int bid = blockIdx.x;
  int t = bid >> 10;
  int tid = threadIdx.x, wave = tid >> 6, lane = tid & 63;
  int quad = lane >> 4, l15 = lane & 15;

  if (t == 3) {  // ---- Wo fp32 -> bf16, 512 blocks ----
    int i = (bid & 511) * 256 + tid;
    const float4* src = (const float4*)Wo + i * 2;
    float4 a = src[0], b = src[1];
    bf16x8 o;
    o[0] = f2bf(a.x); o[1] = f2bf(a.y); o[2] = f2bf(a.z); o[3] = f2bf(a.w);
    o[4] = f2bf(b.x); o[5] = f2bf(b.y); o[6] = f2bf(b.z); o[7] = f2bf(b.w);
    ((bf16x8*)wob)[i] = o;
    return;
  }

  int bh = (bid >> 4) & 63;    // b*16+h
  int st = bid & 15;
  int b = bh >> 4, h = bh & 15;
  int s0 = st * 128;
  const float* inp = (t == 0) ? inpV : (t == 1) ? inpK : inpQ;
  const float* W = (t == 0) ? Wv : (t == 1) ? Wk : Wq;
  // fold score scale AND log2(e) into Wq (attention uses exp2)
  float wscale = (t == 2) ? (0.03125f * 1.4426950408889634f) : 1.0f;

#pragma unroll
  for (int u = 0; u < 2; ++u) {
    int slot = tid + u * 256;
    int row = slot >> 3, g = slot & 7;
    const float4* wp = (const float4*)(W + row * 64 + g * 8);
    float4 w0 = wp[0], w1 = wp[1];
    bf16x8 o;
    o[0] = f2bf(w0.x * wscale); o[1] = f2bf(w0.y * wscale);
    o[2] = f2bf(w0.z * wscale); o[3] = f2bf(w0.w * wscale);
    o[4] = f2bf(w1.x * wscale); o[5] = f2bf(w1.y * wscale);
    o[6] = f2bf(w1.z * wscale); o[7] = f2bf(w1.w * wscale);
    wbuf[row * 8 + (g ^ (row & 7))] = o;
  }
  const float* xg = inp + (b * S_ + s0) * D_ + h * HD_;
#pragma unroll
  for (int u = 0; u < 4; ++u) {
    int slot = tid + u * 256;
    int row = slot >> 3, g = slot & 7;
    const float4* xp = (const float4*)(xg + row * D_ + g * 8);
    float4 x0 = xp[0], x1 = xp[1];
    bf16x8 o;
    o[0] = f2bf(x0.x); o[1] = f2bf(x0.y); o[2] = f2bf(x0.z); o[3] = f2bf(x0.w);
    o[4] = f2bf(x1.x); o[5] = f2bf(x1.y); o[6] = f2bf(x1.z); o[7] = f2bf(x1.w);
    xbuf[row * 8 + (g ^ (row & 7))] = o;
  }
  __syncthreads();

  if (t == 0) {
    f32x4 acc[4][2];
#pragma unroll
    for (int mt = 0; mt < 4; mt++)
#pragma unroll
      for (int nt = 0; nt < 2; nt++) { acc[mt][nt][0]=0.f; acc[mt][nt][1]=0.f; acc[mt][nt][2]=0.f; acc[mt][nt][3]=0.f; }
#pragma unroll
    for (int ks = 0; ks < 2; ++ks) {
      bf16x8 af[4], bfr[2];
#pragma unroll
      for (int mt = 0; mt < 4; ++mt) {
        int row = mt * 16 + l15;
        af[mt] = wbuf[row * 8 + ((ks * 4 + quad) ^ (row & 7))];
      }
#pragma unroll
      for (int nt = 0; nt < 2; ++nt) {
        int row = wave * 32 + nt * 16 + l15;
        bfr[nt] = xbuf[row * 8 + ((ks * 4 + quad) ^ (row & 7))];
      }
#pragma unroll
      for (int mt = 0; mt < 4; ++mt)
#pragma unroll
        for (int nt = 0; nt < 2; ++nt)
          acc[mt][nt] = MFMA32(af[mt], bfr[nt], acc[mt][nt]);
    }
    short* vb = vt + (bh * 64) * S_ + s0 + wave * 32;
#pragma unroll
    for (int mt = 0; mt < 4; ++mt)
#pragma unroll
      for (int nt = 0; nt < 2; ++nt)
#pragma unroll
        for (int r = 0; r < 4; ++r) {
          int e = mt * 16 + quad * 4 + r;
          int s = nt * 16 + l15;
          vb[e * S_ + s] = f2bf(acc[mt][nt][r]);
        }
  } else {
    f32x4 acc[2][4];
#pragma unroll
    for (int mt = 0; mt < 2; mt++)
#pragma unroll
      for (int nt = 0; nt < 4; nt++) { acc[mt][nt][0]=0.f; acc[mt][nt][1]=0.f; acc[mt][nt][2]=0.f; acc[mt][nt][3]=0.f; }
#pragma unroll
    for (int ks = 0; ks < 2; ++ks) {
      bf16x8 af[2], bfr[4];
#pragma unroll
      for (int mt = 0; mt < 2; ++mt) {
        int row = wave * 32 + mt * 16 + l15;
        af[mt] = xbuf[row * 8 + ((ks * 4 + quad) ^ (row & 7))];
      }
#pragma unroll
      for (int nt = 0; nt < 4; ++nt) {
        int row = nt * 16 + l15;
        bfr[nt] = wbuf[row * 8 + ((ks * 4 + quad) ^ (row & 7))];
      }
#pragma unroll
      for (int mt = 0; mt < 2; ++mt)
#pragma unroll
        for (int nt = 0; nt < 4; ++nt)
          acc[mt][nt] = MFMA32(af[mt], bfr[nt], acc[mt][nt]);
    }
    short* ob = ((t == 1) ? kp : qp) + (bh * S_ + s0 + wave * 32) * 64;
#pragma unroll
    for (int mt = 0; mt < 2; ++mt)
#pragma unroll
      for (int nt = 0; nt < 4; ++nt)
#pragma unroll
        for (int r = 0; r < 4; ++r) {
          int s = mt * 16 + quad * 4 + r;
          int e = nt * 16 + l15;
          ob[s * 64 + e] = f2bf(acc[mt][nt][r]);
        }
  }
}

// ---------------- Kernel 2: fused attention (register-staged, LDS-free) ----
// 1 wave/block, 32 q-rows, NO LDS, NO barriers. K/V per head (512KB) is
// L2-resident (8 heads/XCD = 4MB) -> all MFMA fragments are per-lane
// contiguous 16B in kp/vt and load DIRECTLY to registers. K prefetched one
// tile ahead (double set A/B); V issued at body start, consumed at body end
// (QK+exp phase ~430cy covers L2 latency). Issue order V-before-K so PV's
// wait is vmcnt(4) with next K still in flight. 4096 single-wave blocks, no
// LDS -> ~3 waves/SIMD of INDEPENDENTLY-phased streams (R2/R4's barriers
// phase-locked them; that serialized the MFMA and VALU pipes at ~42%/44%).
__global__ __launch_bounds__(64, 3) void attention(
    const short* __restrict__ qp, const short* __restrict__ kp,
    const short* __restrict__ vt, short* __restrict__ ao) {
  int bid = blockIdx.x;
  int qt = bid >> 6;   // 64 q-tiles of 32
  int bh = bid & 63;   // XCD = bid%8 = bh%8 -> whole head on one XCD
  int lane = threadIdx.x & 63;
  int quad = lane >> 4, l15 = lane & 15;

  // Q B-frags: 2 q-groups x (k 0..31 | 32..63), loaded once
  const short* qb = qp + (bh * S_ + qt * 32 + l15) * 64;
  bf16x8 bq[2][2];
#pragma unroll
  for (int qg = 0; qg < 2; ++qg) {
    bq[qg][0] = *(const bf16x8*)(qb + qg * 1024 + quad * 8);
    bq[qg][1] = *(const bf16x8*)(qb + qg * 1024 + 32 + quad * 8);
  }

  const f32x4 fzero = {0.f, 0.f, 0.f, 0.f};
  f32x4 o[2][4];
#pragma unroll
  for (int qg = 0; qg < 2; qg++)
#pragma unroll
    for (int dt = 0; dt < 4; dt++) o[qg][dt] = fzero;
  f32x4 lacc[2];
  lacc[0] = fzero; lacc[1] = fzero;

  short one_bf = (short)0x3F80;
  bf16x8 ones8;
#pragma unroll
  for (int j = 0; j < 8; ++j) ones8[j] = (l15 == 0) ? one_bf : (short)0;

  // permuted QK A-row: nt0 covers keys {0-3,8-11,16-19,24-27}, nt1 the
  // complementary nibbles, so D-row quad*4+r = key quad*8 + nt*4 + r.
  int krp0 = ((l15 >> 2) << 3) + (l15 & 3);      // nt=0 row; nt=1 -> +4 (imm)

  // per-lane register-staging pointers (16B contiguous frags):
  // K[kt*32+krow][kh*32 + quad*8..+7]; V^T[d][kt*32 + quad*8..+7]
  const short* kptr = kp + bh * (S_ * 64) + krp0 * 64 + quad * 8;  // +=2048/kt
  const short* vp0 = vt + bh * (64 * S_) + l15 * S_ + quad * 8;    // +=32/kt
  const short* vp1 = vp0 + 16 * S_;
  const short* vp2 = vp0 + 32 * S_;
  const short* vp3 = vp0 + 48 * S_;

  bf16x8 akA[2][2], akB[2][2], bv[4];

#define ISSUE_K(SET) do {                                                   \
    ak##SET[0][0] = *(const bf16x8*)(kptr);                                 \
    ak##SET[0][1] = *(const bf16x8*)(kptr + 32);                            \
    ak##SET[1][0] = *(const bf16x8*)(kptr + 256);                           \
    ak##SET[1][1] = *(const bf16x8*)(kptr + 288);                           \
    kptr += 2048;                                                           \
  } while (0)

#define ISSUE_V() do {                                                      \
    bv[0] = *(const bf16x8*)(vp0);                                          \
    bv[1] = *(const bf16x8*)(vp1);                                          \
    bv[2] = *(const bf16x8*)(vp2);                                          \
    bv[3] = *(const bf16x8*)(vp3);                                          \
    vp0 += 32; vp1 += 32; vp2 += 32; vp3 += 32;                             \
  } while (0)

#define COMPUTE(SET) do {                                                   \
    union Frag { unsigned u[4]; bf16x8 v; } pa0, pa1;                       \
    _Pragma("unroll")                                                       \
    for (int nt = 0; nt < 2; ++nt) {                                        \
      f32x4 c0 = MFMA32(ak##SET[nt][0], bq[0][0], fzero);                   \
      f32x4 c1 = MFMA32(ak##SET[nt][0], bq[1][0], fzero);                   \
      c0 = MFMA32(ak##SET[nt][1], bq[0][1], c0);                            \
      c1 = MFMA32(ak##SET[nt][1], bq[1][1], c1);                            \
      float e00 = fast_exp2(c0[0]), e01 = fast_exp2(c0[1]);                 \
      float e02 = fast_exp2(c0[2]), e03 = fast_exp2(c0[3]);                 \
      float e10 = fast_exp2(c1[0]), e11 = fast_exp2(c1[1]);                 \
      float e12 = fast_exp2(c1[2]), e13 = fast_exp2(c1[3]);                 \
      pa0.u[nt * 2 + 0] = pack_hi16(e00, e01);                              \
      pa0.u[nt * 2 + 1] = pack_hi16(e02, e03);                              \
      pa1.u[nt * 2 + 0] = pack_hi16(e10, e11);                              \
      pa1.u[nt * 2 + 1] = pack_hi16(e12, e13);                              \
    }                                                                       \
    __builtin_amdgcn_s_setprio(1);                                          \
    lacc[0] = MFMA32(pa0.v, ones8, lacc[0]);                                \
    lacc[1] = MFMA32(pa1.v, ones8, lacc[1]);                                \
    _Pragma("unroll")                                                       \
    for (int dt = 0; dt < 4; ++dt) {                                        \
      o[0][dt] = MFMA32(pa0.v, bv[dt], o[0][dt]);                           \
      o[1][dt] = MFMA32(pa1.v, bv[dt], o[1][dt]);                           \
    }                                                                       \
    __builtin_amdgcn_s_setprio(0);                                          \
  } while (0)

  ISSUE_K(A);  // tile 0
  for (int kt = 0; kt < 64; kt += 2) {
    ISSUE_V();                          // V(kt)   (older than K prefetch)
    ISSUE_K(B);                         // K(kt+1)
    __builtin_amdgcn_sched_barrier(0);
    COMPUTE(A);                         // tile kt
    ISSUE_V();                          // V(kt+1)
    ISSUE_K(A);                         // K(kt+2) (kt=62: stray in-bounds ws)
    __builtin_amdgcn_sched_barrier(0);
    COMPUTE(B);                         // tile kt+1
  }
#undef ISSUE_K
#undef ISSUE_V
#undef COMPUTE

  // epilogue: lsum[q=quad*4+r] sits at lane (quad, l15==0), reg r
  int b = bh >> 4, h = bh & 15;
#pragma unroll
  for (int qg = 0; qg < 2; ++qg) {
    float inv[4];
#pragma unroll
    for (int r = 0; r < 4; ++r) {
      float ls = __shfl(lacc[qg][r], lane & 48, 64);
      inv[r] = fast_rcp(ls);
    }
#pragma unroll
    for (int dt = 0; dt < 4; ++dt)
#pragma unroll
      for (int r = 0; r < 4; ++r) {
        int srow = qt * 32 + qg * 16 + quad * 4 + r;
        ao[(b * S_ + srow) * D_ + h * 64 + dt * 16 + l15] =
            f2bf(o[qg][dt][r] * inv[r]);
      }
  }
}

// ---------------- Kernel 3: output projection GEMM + bias ----------------
// DMA-dbuf single-barrier K-loop.
__global__ __launch_bounds__(256) void outproj(const short* __restrict__ A,
                                               const short* __restrict__ Bw,
                                               const float* __restrict__ bo,
                                               float* __restrict__ out) {
  __shared__ bf16x8 sa[2][1024];  // 2 x 16KB
  __shared__ bf16x8 sb[2][1024];  // 2 x 16KB
  int bid = blockIdx.x;
  int m0 = (bid >> 3) * 128, n0 = (bid & 7) * 128;
  int tid = threadIdx.x, wave = tid >> 6, lane = tid & 63;
  int quad = lane >> 4, l15 = lane & 15;
  int wm = (wave >> 1) * 64, wn = (wave & 1) * 64;
  f32x4 acc[4][4];
#pragma unroll
  for (int mt = 0; mt < 4; mt++)
#pragma unroll
    for (int nt = 0; nt < 4; nt++) { acc[mt][nt][0]=0.f; acc[mt][nt][1]=0.f; acc[mt][nt][2]=0.f; acc[mt][nt][3]=0.f; }

  const short* asrc[4];
  const short* bsrc[4];
#pragma unroll
  for (int u = 0; u < 4; ++u) {
    int slot = tid + u * 256;
    int row = slot >> 3, g = (slot & 7) ^ (row & 7);
    asrc[u] = A + (m0 + row) * 1024 + g * 8;
    bsrc[u] = Bw + (n0 + row) * 1024 + g * 8;
  }
#pragma unroll
  for (int u = 0; u < 4; ++u) {
    gl_lds16(asrc[u], &sa[0][tid + u * 256]);
    gl_lds16(bsrc[u], &sb[0][tid + u * 256]);
  }

  int p = 0;
  for (int k0 = 0; k0 < 1024; k0 += 64) {
    __syncthreads();
    int kn = (k0 + 64) & 1023;
#pragma unroll
    for (int u = 0; u < 4; ++u) {
      gl_lds16(asrc[u] + kn, &sa[p ^ 1][tid + u * 256]);
      gl_lds16(bsrc[u] + kn, &sb[p ^ 1][tid + u * 256]);
    }
#pragma unroll
    for (int ks = 0; ks < 2; ++ks) {
      bf16x8 af[4], bf[4];
#pragma unroll
      for (int mt = 0; mt < 4; ++mt) {
        int row = wm + mt * 16 + l15;
        af[mt] = sa[p][row * 8 + ((ks * 4 + quad) ^ (row & 7))];
      }
#pragma unroll
      for (int nt = 0; nt < 4; ++nt) {
        int row = wn + nt * 16 + l15;
        bf[nt] = sb[p][row * 8 + ((ks * 4 + quad) ^ (row & 7))];
      }
#pragma unroll
      for (int mt = 0; mt < 4; ++mt)
#pragma unroll
        for (int nt = 0; nt < 4; ++nt)
          acc[mt][nt] = MFMA32(af[mt], bf[nt], acc[mt][nt]);
    }
    p ^= 1;
  }
#pragma unroll
  for (int nt = 0; nt < 4; ++nt) {
    int n = n0 + wn + nt * 16 + l15;
    float bov = bo[n];
#pragma unroll
    for (int mt = 0; mt < 4; ++mt)
#pragma unroll
      for (int r = 0; r < 4; r++) {
        int m = m0 + wm + mt * 16 + quad * 4 + r;
        out[m * 1024 + n] = acc[mt][nt][r] + bov;
      }
  }
}

extern "C" void kernel_launch(void* const* d_in, const int* in_sizes, int n_in,
                              void* d_out, int out_size, void* d_ws,
                              size_t ws_size, hipStream_t stream) {
  const float* inpV = (const float*)d_in[0];
  const float* inpK = (const float*)d_in[1];
  const float* inpQ = (const float*)d_in[2];
  const float* Wv = (const float*)d_in[3];
  const float* Wk = (const float*)d_in[4];
  const float* Wq = (const float*)d_in[5];
  const float* Wo = (const float*)d_in[6];
  const float* bo = (const float*)d_in[7];
  float* out = (float*)d_out;

  char* ws = (char*)d_ws;
  short* vt = (short*)(ws);                       // 16MB  [B,H,64,S]
  short* kp = (short*)(ws + (16u << 20));         // 16MB  [B,H,S,64]
  short* qp = (short*)(ws + (32u << 20));         // 16MB  [B,H,S,64]
  short* ao = (short*)(ws + (48u << 20));         // 16MB  [B*S, D] bf16
  short* wob = (short*)(ws + (64u << 20));        // 2MB   Wo bf16

  qkv_proj2<<<dim3(3584), dim3(256), 0, stream>>>(inpV, inpK, inpQ, Wv, Wk, Wq,
                                                  Wo, wob, vt, kp, qp);
  attention<<<dim3(4096), dim3(64), 0, stream>>>(qp, kp, vt, ao);
  outproj<<<dim3(512), dim3(256), 0, stream>>>(ao, wob, bo, out);
}

// Round 7
// 259.277 us; speedup vs baseline: 1.6301x; 1.6301x over previous
//
#include <hip/hip_runtime.h>
#include <hip/hip_bf16.h>

#define B_ 4
#define S_ 2048
#define D_ 1024
#define H_ 16
#define HD_ 64

typedef __attribute__((ext_vector_type(8))) short bf16x8;
typedef __attribute__((ext_vector_type(4))) short bf16x4;
typedef __attribute__((ext_vector_type(4))) float f32x4;

#define MFMA32(a, b, c) __builtin_amdgcn_mfma_f32_16x16x32_bf16(a, b, c, 0, 0, 0)

// K-buf byte-group swizzle: varies g's bit2 across the krows of one QK
// A-read (krow bit2 is fixed per nt) -> conflict-free QK ds_read_b128.
#define KSWZ(r) ((((r) & 3)) ^ ((((r) >> 3) & 1) << 2))

__device__ __forceinline__ float fast_exp2(float x) {
#if __has_builtin(__builtin_amdgcn_exp2f)
  return __builtin_amdgcn_exp2f(x);
#else
  return exp2f(x);
#endif
}

__device__ __forceinline__ float fast_rcp(float x) {
#if __has_builtin(__builtin_amdgcn_rcpf)
  return __builtin_amdgcn_rcpf(x);
#else
  return 1.0f / x;
#endif
}

__device__ __forceinline__ short f2bf(float x) {
  union { float f; unsigned u; } v; v.f = x;
  unsigned r = (v.u + 0x7fffu + ((v.u >> 16) & 1u)) >> 16;
  return (short)(r & 0xffffu);
}

// single v_perm_b32 truncation pack: dst = (hi16(b)<<16)|hi16(a).
// Truncation bias cancels in softmax ratio (lsum sums the SAME truncated P).
__device__ __forceinline__ unsigned pack_hi16(float a, float b) {
  union { float f; unsigned u; } ua, ub; ua.f = a; ub.f = b;
  return __builtin_amdgcn_perm(ub.u, ua.u, 0x07060302u);
}

// async global->LDS DMA, 16 B per lane; LDS dest = wave-uniform base + lane*16.
__device__ __forceinline__ void gl_lds16(const short* g, void* l) {
  __builtin_amdgcn_global_load_lds(
      (const __attribute__((address_space(1))) unsigned*)(const void*)g,
      (__attribute__((address_space(3))) unsigned*)l, 16, 0, 0);
}

// ---------------- Kernel 1: QKV projections via MFMA (+ fused Wo convert) ---
// t = bid>>10: 0=V, 1=K, 2=Q, 3=Wo-convert. Operand-SWAPPED MFMA epilogue:
// C row-dim comes from the A operand and the 4 acc regs walk the row dim, so
// pick A = whichever matrix indexes the OUTPUT MINOR dim (V^T minor=s -> A=x;
// K/Q minor=e -> A=W). Each lane then packs its 4 regs into ONE bf16x4 8B
// store (8 store instrs/wave vs 64 scalar 2B stores -> was the qkv pole).
__global__ __launch_bounds__(256) void qkv_proj2(
    const float* __restrict__ inpV, const float* __restrict__ inpK,
    const float* __restrict__ inpQ, const float* __restrict__ Wv,
    const float* __restrict__ Wk, const float* __restrict__ Wq,
    const float* __restrict__ Wo, short* __restrict__ wob,
    short* __restrict__ vt, short* __restrict__ kp, short* __restrict__ qp) {
  __shared__ bf16x8 xbuf[1024];  // 128 rows x 8 groups (16KB), g^=row&7
  __shared__ bf16x8 wbuf[512];   // 64 rows x 8 groups (8KB), g^=row&7
  int bid = blockIdx.x;
  int t = bid >> 10;
  int tid = threadIdx.x, wave = tid >> 6, lane = tid & 63;
  int quad = lane >> 4, l15 = lane & 15;

  if (t == 3) {  // ---- Wo fp32 -> bf16, 512 blocks ----
    int i = (bid & 511) * 256 + tid;
    const float4* src = (const float4*)Wo + i * 2;
    float4 a = src[0], b = src[1];
    bf16x8 o;
    o[0] = f2bf(a.x); o[1] = f2bf(a.y); o[2] = f2bf(a.z); o[3] = f2bf(a.w);
    o[4] = f2bf(b.x); o[5] = f2bf(b.y); o[6] = f2bf(b.z); o[7] = f2bf(b.w);
    ((bf16x8*)wob)[i] = o;
    return;
  }

  int bh = (bid >> 4) & 63;    // b*16+h
  int st = bid & 15;
  int b = bh >> 4, h = bh & 15;
  int s0 = st * 128;
  const float* inp = (t == 0) ? inpV : (t == 1) ? inpK : inpQ;
  const float* W = (t == 0) ? Wv : (t == 1) ? Wk : Wq;
  // fold score scale AND log2(e) into Wq (attention uses exp2)
  float wscale = (t == 2) ? (0.03125f * 1.4426950408889634f) : 1.0f;

#pragma unroll
  for (int u = 0; u < 2; ++u) {
    int slot = tid + u * 256;
    int row = slot >> 3, g = slot & 7;
    const float4* wp = (const float4*)(W + row * 64 + g * 8);
    float4 w0 = wp[0], w1 = wp[1];
    bf16x8 o;
    o[0] = f2bf(w0.x * wscale); o[1] = f2bf(w0.y * wscale);
    o[2] = f2bf(w0.z * wscale); o[3] = f2bf(w0.w * wscale);
    o[4] = f2bf(w1.x * wscale); o[5] = f2bf(w1.y * wscale);
    o[6] = f2bf(w1.z * wscale); o[7] = f2bf(w1.w * wscale);
    wbuf[row * 8 + (g ^ (row & 7))] = o;
  }
  const float* xg = inp + (b * S_ + s0) * D_ + h * HD_;
#pragma unroll
  for (int u = 0; u < 4; ++u) {
    int slot = tid + u * 256;
    int row = slot >> 3, g = slot & 7;
    const float4* xp = (const float4*)(xg + row * D_ + g * 8);
    float4 x0 = xp[0], x1 = xp[1];
    bf16x8 o;
    o[0] = f2bf(x0.x); o[1] = f2bf(x0.y); o[2] = f2bf(x0.z); o[3] = f2bf(x0.w);
    o[4] = f2bf(x1.x); o[5] = f2bf(x1.y); o[6] = f2bf(x1.z); o[7] = f2bf(x1.w);
    xbuf[row * 8 + (g ^ (row & 7))] = o;
  }
  __syncthreads();

  if (t == 0) {
    // V^T output vt[e][s] (minor = s): M=s (A=x), N=e (B=W)
    f32x4 acc[2][4];
#pragma unroll
    for (int mt = 0; mt < 2; mt++)
#pragma unroll
      for (int nt = 0; nt < 4; nt++) { acc[mt][nt][0]=0.f; acc[mt][nt][1]=0.f; acc[mt][nt][2]=0.f; acc[mt][nt][3]=0.f; }
#pragma unroll
    for (int ks = 0; ks < 2; ++ks) {
      bf16x8 af[2], bfr[4];
#pragma unroll
      for (int mt = 0; mt < 2; ++mt) {
        int row = wave * 32 + mt * 16 + l15;
        af[mt] = xbuf[row * 8 + ((ks * 4 + quad) ^ (row & 7))];
      }
#pragma unroll
      for (int nt = 0; nt < 4; ++nt) {
        int row = nt * 16 + l15;
        bfr[nt] = wbuf[row * 8 + ((ks * 4 + quad) ^ (row & 7))];
      }
#pragma unroll
      for (int mt = 0; mt < 2; ++mt)
#pragma unroll
        for (int nt = 0; nt < 4; ++nt)
          acc[mt][nt] = MFMA32(af[mt], bfr[nt], acc[mt][nt]);
    }
    short* vb = vt + bh * 64 * S_;
#pragma unroll
    for (int mt = 0; mt < 2; ++mt)
#pragma unroll
      for (int nt = 0; nt < 4; ++nt) {
        bf16x4 pk;
#pragma unroll
        for (int r = 0; r < 4; ++r) pk[r] = f2bf(acc[mt][nt][r]);
        int e = nt * 16 + l15;
        int s = s0 + wave * 32 + mt * 16 + quad * 4;
        *(bf16x4*)(vb + e * S_ + s) = pk;
      }
  } else {
    // K/Q output [s][e] (minor = e): M=e (A=W), N=s (B=x)
    f32x4 acc[4][2];
#pragma unroll
    for (int mt = 0; mt < 4; mt++)
#pragma unroll
      for (int nt = 0; nt < 2; nt++) { acc[mt][nt][0]=0.f; acc[mt][nt][1]=0.f; acc[mt][nt][2]=0.f; acc[mt][nt][3]=0.f; }
#pragma unroll
    for (int ks = 0; ks < 2; ++ks) {
      bf16x8 af[4], bfr[2];
#pragma unroll
      for (int mt = 0; mt < 4; ++mt) {
        int row = mt * 16 + l15;
        af[mt] = wbuf[row * 8 + ((ks * 4 + quad) ^ (row & 7))];
      }
#pragma unroll
      for (int nt = 0; nt < 2; ++nt) {
        int row = wave * 32 + nt * 16 + l15;
        bfr[nt] = xbuf[row * 8 + ((ks * 4 + quad) ^ (row & 7))];
      }
#pragma unroll
      for (int mt = 0; mt < 4; ++mt)
#pragma unroll
        for (int nt = 0; nt < 2; ++nt)
          acc[mt][nt] = MFMA32(af[mt], bfr[nt], acc[mt][nt]);
    }
    short* ob = ((t == 1) ? kp : qp) + bh * S_ * 64;
#pragma unroll
    for (int mt = 0; mt < 4; ++mt)
#pragma unroll
      for (int nt = 0; nt < 2; ++nt) {
        bf16x4 pk;
#pragma unroll
        for (int r = 0; r < 4; ++r) pk[r] = f2bf(acc[mt][nt][r]);
        int s = s0 + wave * 32 + nt * 16 + l15;
        int e = mt * 16 + quad * 4;
        *(bf16x4*)(ob + s * 64 + e) = pk;
      }
  }
}

// ---------------- Kernel 2: fused attention (barrier-free, R3-measured) ----
// 1 wave per block, 64 q-rows per wave (4 q-groups), private 2x8KB K/V
// double-buffer per wave, ZERO __syncthreads. Ordering is per-wave counted
// vmcnt: issue tile T+1's 8 DMAs, then s_waitcnt vmcnt(8) => tile T landed,
// T+1 still in flight. (Best-measured attention variant: 78.8us; the
// register-staged R5 variant regressed 3x — L2 thrash + exposed HBM latency.
// DMA->LDS staging is structural latency decoupling; keep it.)
__global__ __launch_bounds__(64, 2) void attention(
    const short* __restrict__ qp, const short* __restrict__ kp,
    const short* __restrict__ vt, short* __restrict__ ao) {
  __shared__ bf16x8 kbuf[2][256];  // 32 krows x 8 groups (4KB each)
  __shared__ bf16x8 vbuf[2][256];  // 64 drows x 4 groups (4KB each)
  int bid = blockIdx.x;
  int qt = bid >> 6;   // 32 q-tiles of 64
  int bh = bid & 63;   // XCD = bid%8 = bh%8 -> whole head on one XCD
  int lane = threadIdx.x & 63;
  int quad = lane >> 4, l15 = lane & 15;

  // Q B-frags: 4 q-groups x (k 0..31 | 32..63), loaded once
  const short* qb = qp + (bh * S_ + qt * 64 + l15) * 64;
  bf16x8 bq[4][2];
#pragma unroll
  for (int qg = 0; qg < 4; ++qg) {
    bq[qg][0] = *(const bf16x8*)(qb + qg * 1024 + quad * 8);
    bq[qg][1] = *(const bf16x8*)(qb + qg * 1024 + 32 + quad * 8);
  }

  const f32x4 fzero = {0.f, 0.f, 0.f, 0.f};
  f32x4 o[4][4];
#pragma unroll
  for (int qg = 0; qg < 4; qg++)
#pragma unroll
    for (int dt = 0; dt < 4; dt++) o[qg][dt] = fzero;
  f32x4 lacc[4];
#pragma unroll
  for (int qg = 0; qg < 4; qg++) lacc[qg] = fzero;

  short one_bf = (short)0x3F80;
  bf16x8 ones8;
#pragma unroll
  for (int j = 0; j < 8; ++j) ones8[j] = (l15 == 0) ? one_bf : (short)0;

  const short* kg = kp + bh * S_ * 64;
  const short* vg = vt + bh * 64 * S_;

  // staging source addresses (pre-swizzled global so linear-dest DMA lands
  // chunk (g ^ swz(row)) at slot g). K: row=slot>>3, g=slot&7, KSWZ.
  // V: row=slot>>2, g=slot&3, g^(row&3).
  const short* ksrc[4];
  const short* vsrc[4];
#pragma unroll
  for (int u = 0; u < 4; ++u) {
    int slot = lane + u * 64;
    int kr = slot >> 3, kgg = (slot & 7) ^ KSWZ(kr);
    ksrc[u] = kg + kr * 64 + kgg * 8;              // + kt*2048
    int vr = slot >> 2, vgg = (slot & 3) ^ (vr & 3);
    vsrc[u] = vg + vr * S_ + vgg * 8;              // + kt*32
  }

  // prologue: DMA tile 0 into buffer 0 (8 outstanding)
#pragma unroll
  for (int u = 0; u < 4; ++u) gl_lds16(ksrc[u], &kbuf[0][u * 64]);
#pragma unroll
  for (int u = 0; u < 4; ++u) gl_lds16(vsrc[u], &vbuf[0][u * 64]);

  // permuted QK A-row: nt0 covers keys {0-3,8-11,16-19,24-27}, nt1 the
  // complementary nibbles, so D-row quad*4+r = key quad*8 + nt*4 + r.
  int krp0 = ((l15 >> 2) << 3) + (l15 & 3);      // nt=0 row; nt=1 -> +4

  // hoisted, loop-invariant LDS slots
  int aslot0[2], aslot1[2], vslot[4];
#pragma unroll
  for (int nt = 0; nt < 2; ++nt) {
    int krow = krp0 + nt * 4;
    aslot0[nt] = krow * 8 + ((0 + quad) ^ KSWZ(krow));
    aslot1[nt] = krow * 8 + ((4 + quad) ^ KSWZ(krow));
  }
#pragma unroll
  for (int dt = 0; dt < 4; ++dt) {
    int d = dt * 16 + l15;
    vslot[dt] = d * 4 + (quad ^ (d & 3));
  }

#define ATTN_BODY(P, T)                                                     \
  do {                                                                      \
    int ktn = ((T) + 1) & 63; /* wrap: redundant in-bounds last-iter load */\
    _Pragma("unroll")                                                       \
    for (int u = 0; u < 4; ++u)                                             \
      gl_lds16(ksrc[u] + ktn * 2048, &kbuf[(P) ^ 1][u * 64]);               \
    _Pragma("unroll")                                                       \
    for (int u = 0; u < 4; ++u)                                             \
      gl_lds16(vsrc[u] + ktn * 32, &vbuf[(P) ^ 1][u * 64]);                 \
    asm volatile("s_waitcnt vmcnt(8)" ::: "memory"); /* tile T landed */    \
    __builtin_amdgcn_sched_barrier(0);                                      \
    union Frag { unsigned u[4]; bf16x8 v; } pa[4];                          \
    _Pragma("unroll")                                                       \
    for (int nt = 0; nt < 2; ++nt) {                                        \
      bf16x8 ak0 = kbuf[(P)][aslot0[nt]];                                   \
      bf16x8 ak1 = kbuf[(P)][aslot1[nt]];                                   \
      _Pragma("unroll")                                                     \
      for (int qg = 0; qg < 4; ++qg) {                                      \
        f32x4 c = MFMA32(ak0, bq[qg][0], fzero);                            \
        c = MFMA32(ak1, bq[qg][1], c);                                      \
        float e0 = fast_exp2(c[0]), e1 = fast_exp2(c[1]);                   \
        float e2 = fast_exp2(c[2]), e3 = fast_exp2(c[3]);                   \
        pa[qg].u[nt * 2 + 0] = pack_hi16(e0, e1);                           \
        pa[qg].u[nt * 2 + 1] = pack_hi16(e2, e3);                           \
      }                                                                     \
    }                                                                       \
    __builtin_amdgcn_s_setprio(1);                                          \
    _Pragma("unroll")                                                       \
    for (int qg = 0; qg < 4; ++qg)                                          \
      lacc[qg] = MFMA32(pa[qg].v, ones8, lacc[qg]);                         \
    _Pragma("unroll")                                                       \
    for (int dt = 0; dt < 4; ++dt) {                                        \
      bf16x8 bv = vbuf[(P)][vslot[dt]];                                     \
      _Pragma("unroll")                                                     \
      for (int qg = 0; qg < 4; ++qg)                                        \
        o[qg][dt] = MFMA32(pa[qg].v, bv, o[qg][dt]);                        \
    }                                                                       \
    __builtin_amdgcn_s_setprio(0);                                          \
  } while (0)

  for (int kt = 0; kt < 64; kt += 2) {
    ATTN_BODY(0, kt);
    ATTN_BODY(1, kt + 1);
  }
#undef ATTN_BODY

  // drain wrap-around DMAs before LDS is handed to the next block
  asm volatile("s_waitcnt vmcnt(0)" ::: "memory");

  // epilogue: lsum[q=quad*4+r] sits at lane (quad, l15==0), reg r
  int b = bh >> 4, h = bh & 15;
#pragma unroll
  for (int qg = 0; qg < 4; ++qg) {
    float inv[4];
#pragma unroll
    for (int r = 0; r < 4; ++r) {
      float ls = __shfl(lacc[qg][r], lane & 48, 64);
      inv[r] = fast_rcp(ls);
    }
#pragma unroll
    for (int dt = 0; dt < 4; ++dt)
#pragma unroll
      for (int r = 0; r < 4; ++r) {
        int srow = qt * 64 + qg * 16 + quad * 4 + r;
        ao[(b * S_ + srow) * D_ + h * 64 + dt * 16 + l15] =
            f2bf(o[qg][dt][r] * inv[r]);
      }
  }
}

// ---------------- Kernel 3: output projection GEMM + bias ----------------
// DMA-dbuf single-barrier K-loop.
__global__ __launch_bounds__(256) void outproj(const short* __restrict__ A,
                                               const short* __restrict__ Bw,
                                               const float* __restrict__ bo,
                                               float* __restrict__ out) {
  __shared__ bf16x8 sa[2][1024];  // 2 x 16KB
  __shared__ bf16x8 sb[2][1024];  // 2 x 16KB
  int bid = blockIdx.x;
  int m0 = (bid >> 3) * 128, n0 = (bid & 7) * 128;
  int tid = threadIdx.x, wave = tid >> 6, lane = tid & 63;
  int quad = lane >> 4, l15 = lane & 15;
  int wm = (wave >> 1) * 64, wn = (wave & 1) * 64;
  f32x4 acc[4][4];
#pragma unroll
  for (int mt = 0; mt < 4; mt++)
#pragma unroll
    for (int nt = 0; nt < 4; nt++) { acc[mt][nt][0]=0.f; acc[mt][nt][1]=0.f; acc[mt][nt][2]=0.f; acc[mt][nt][3]=0.f; }

  const short* asrc[4];
  const short* bsrc[4];
#pragma unroll
  for (int u = 0; u < 4; ++u) {
    int slot = tid + u * 256;
    int row = slot >> 3, g = (slot & 7) ^ (row & 7);
    asrc[u] = A + (m0 + row) * 1024 + g * 8;
    bsrc[u] = Bw + (n0 + row) * 1024 + g * 8;
  }
#pragma unroll
  for (int u = 0; u < 4; ++u) {
    gl_lds16(asrc[u], &sa[0][tid + u * 256]);
    gl_lds16(bsrc[u], &sb[0][tid + u * 256]);
  }

  int p = 0;
  for (int k0 = 0; k0 < 1024; k0 += 64) {
    __syncthreads();
    int kn = (k0 + 64) & 1023;
#pragma unroll
    for (int u = 0; u < 4; ++u) {
      gl_lds16(asrc[u] + kn, &sa[p ^ 1][tid + u * 256]);
      gl_lds16(bsrc[u] + kn, &sb[p ^ 1][tid + u * 256]);
    }
#pragma unroll
    for (int ks = 0; ks < 2; ++ks) {
      bf16x8 af[4], bf[4];
#pragma unroll
      for (int mt = 0; mt < 4; ++mt) {
        int row = wm + mt * 16 + l15;
        af[mt] = sa[p][row * 8 + ((ks * 4 + quad) ^ (row & 7))];
      }
#pragma unroll
      for (int nt = 0; nt < 4; ++nt) {
        int row = wn + nt * 16 + l15;
        bf[nt] = sb[p][row * 8 + ((ks * 4 + quad) ^ (row & 7))];
      }
#pragma unroll
      for (int mt = 0; mt < 4; ++mt)
#pragma unroll
        for (int nt = 0; nt < 4; ++nt)
          acc[mt][nt] = MFMA32(af[mt], bf[nt], acc[mt][nt]);
    }
    p ^= 1;
  }
#pragma unroll
  for (int nt = 0; nt < 4; ++nt) {
    int n = n0 + wn + nt * 16 + l15;
    float bov = bo[n];
#pragma unroll
    for (int mt = 0; mt < 4; ++mt)
#pragma unroll
      for (int r = 0; r < 4; r++) {
        int m = m0 + wm + mt * 16 + quad * 4 + r;
        out[m * 1024 + n] = acc[mt][nt][r] + bov;
      }
  }
}

extern "C" void kernel_launch(void* const* d_in, const int* in_sizes, int n_in,
                              void* d_out, int out_size, void* d_ws,
                              size_t ws_size, hipStream_t stream) {
  const float* inpV = (const float*)d_in[0];
  const float* inpK = (const float*)d_in[1];
  const float* inpQ = (const float*)d_in[2];
  const float* Wv = (const float*)d_in[3];
  const float* Wk = (const float*)d_in[4];
  const float* Wq = (const float*)d_in[5];
  const float* Wo = (const float*)d_in[6];
  const float* bo = (const float*)d_in[7];
  float* out = (float*)d_out;

  char* ws = (char*)d_ws;
  short* vt = (short*)(ws);                       // 16MB  [B,H,64,S]
  short* kp = (short*)(ws + (16u << 20));         // 16MB  [B,H,S,64]
  short* qp = (short*)(ws + (32u << 20));         // 16MB  [B,H,S,64]
  short* ao = (short*)(ws + (48u << 20));         // 16MB  [B*S, D] bf16
  short* wob = (short*)(ws + (64u << 20));        // 2MB   Wo bf16

  qkv_proj2<<<dim3(3584), dim3(256), 0, stream>>>(inpV, inpK, inpQ, Wv, Wk, Wq,
                                                  Wo, wob, vt, kp, qp);
  attention<<<dim3(2048), dim3(64), 0, stream>>>(qp, kp, vt, ao);
  outproj<<<dim3(512), dim3(256), 0, stream>>>(ao, wob, bo, out);
}